// Round 10
// baseline (192.113 us; speedup 1.0000x reference)
//
#include <hip/hip_runtime.h>
#include <math.h>

#define B_ 4
#define T_ 2048
#define C_ 1024
#define H_ 128
#define RCHUNK 128                 // rows per stats chunk == stats t-tile
#define NCHUNK (T_ / RCHUNK)       // 16 chunks

typedef unsigned short u16;
typedef unsigned int   u32;
typedef short short8  __attribute__((ext_vector_type(8)));  // 8 bf16 = 4 VGPRs
typedef short short4v __attribute__((ext_vector_type(4)));  // 8B
typedef float floatx4 __attribute__((ext_vector_type(4)));  // MFMA C/D

// fp32 -> bf16 round-to-nearest-even
__device__ __forceinline__ u16 f2bf(float f) {
    union { float f; u32 u; } v; v.f = f;
    return (u16)((v.u + 0x7fffu + ((v.u >> 16) & 1u)) >> 16);
}

// ---------------------------------------------------------------------------
// Kernel A1: W [C][H] fp32 -> Wt [3][H][C] bf16 (transposed for MFMA B-frags).
// ---------------------------------------------------------------------------
__global__ __launch_bounds__(256) void convert_w_kernel(
    const float* __restrict__ Wq, const float* __restrict__ Wk,
    const float* __restrict__ Wv, u16* __restrict__ Wt)
{
    const int k0 = blockIdx.x * 64, n0 = blockIdx.y * 64, widx = blockIdx.z;
    const float* W = (widx == 0) ? Wq : (widx == 1) ? Wk : Wv;

    __shared__ float ts[64][68];                // +4 pad
    for (int i = threadIdx.x; i < 64 * 16; i += 256) {
        int r = i >> 4, c4 = i & 15;
        float4 v = *(const float4*)&W[(size_t)(k0 + r) * H_ + n0 + c4 * 4];
        ts[r][c4 * 4 + 0] = v.x; ts[r][c4 * 4 + 1] = v.y;
        ts[r][c4 * 4 + 2] = v.z; ts[r][c4 * 4 + 3] = v.w;
    }
    __syncthreads();
    for (int i = threadIdx.x; i < 64 * 16; i += 256) {
        int n = i >> 4, k4 = i & 15;
        short4v o;
        #pragma unroll
        for (int j = 0; j < 4; ++j) o[j] = (short)f2bf(ts[k4 * 4 + j][n]);
        *(short4v*)&Wt[(size_t)widx * H_ * C_ + (size_t)(n0 + n) * C_ + k0 + k4 * 4] = o;
    }
}

// ---------------------------------------------------------------------------
// Kernel A2 (MFMA): QKV projection, A staged straight from fp32 x with
// in-register bf16 conversion.  grid (M/64, 3); block 256 = 4 waves;
// tile 64(m) x 128(n); BK=128.  widx 0/1 -> Q,K row-major; widx 2 -> V
// stored TRANSPOSED directly (C/D gives 4 consecutive t per lane).
// ---------------------------------------------------------------------------
__global__ __launch_bounds__(256) void qkv_gemm_kernel(
    const float* __restrict__ x, const u16* __restrict__ Wt,
    u16* __restrict__ Qb, u16* __restrict__ Kb, u16* __restrict__ Vt)
{
    const int m0   = blockIdx.x * 64;
    const int widx = blockIdx.y;
    const u16* Wg = Wt + (size_t)widx * H_ * C_;

    __shared__ u16 As[64 * 136];                // 17.4 KB
    __shared__ u16 Bs[128 * 136];               // 34.8 KB

    const int w    = threadIdx.x >> 6;          // wave -> m rows [16w,16w+16)
    const int lane = threadIdx.x & 63;
    const int q    = lane >> 4, r = lane & 15;

    floatx4 acc[8] = {};                        // 16(m) x 128(n)

    for (int k0 = 0; k0 < C_; k0 += 128) {
        for (int i = threadIdx.x; i < 64 * 16; i += 256) {
            int rr = i >> 4, c = i & 15;
            const float* xg = &x[(size_t)(m0 + rr) * C_ + k0 + c * 8];
            float4 a = *(const float4*)xg;
            float4 b = *(const float4*)(xg + 4);
            short8 o;
            o[0]=(short)f2bf(a.x); o[1]=(short)f2bf(a.y);
            o[2]=(short)f2bf(a.z); o[3]=(short)f2bf(a.w);
            o[4]=(short)f2bf(b.x); o[5]=(short)f2bf(b.y);
            o[6]=(short)f2bf(b.z); o[7]=(short)f2bf(b.w);
            *(short8*)&As[rr * 136 + c * 8] = o;
        }
        for (int i = threadIdx.x; i < 128 * 16; i += 256) {
            int rr = i >> 4, c = i & 15;
            *(float4*)&Bs[rr * 136 + c * 8] =
                *(const float4*)&Wg[(size_t)rr * C_ + k0 + c * 8];
        }
        __syncthreads();

        #pragma unroll
        for (int kk = 0; kk < 4; ++kk) {
            short8 af = *(const short8*)&As[(16 * w + r) * 136 + kk * 32 + q * 8];
            #pragma unroll
            for (int nt = 0; nt < 8; ++nt) {
                short8 bf = *(const short8*)&Bs[(16 * nt + r) * 136 + kk * 32 + q * 8];
                acc[nt] = __builtin_amdgcn_mfma_f32_16x16x32_bf16(af, bf, acc[nt], 0, 0, 0);
            }
        }
        __syncthreads();
    }

    if (widx == 2) {
        const int bb  = m0 / T_;                // 64-row tile never spans b
        const int tt0 = (m0 - bb * T_) + 16 * w + q * 4;
        #pragma unroll
        for (int nt = 0; nt < 8; ++nt) {
            short4v o;
            #pragma unroll
            for (int reg = 0; reg < 4; ++reg) o[reg] = (short)f2bf(acc[nt][reg]);
            *(short4v*)&Vt[((size_t)bb * H_ + 16 * nt + r) * T_ + tt0] = o;
        }
    } else {
        u16* dst = (widx == 0) ? Qb : Kb;
        #pragma unroll
        for (int nt = 0; nt < 8; ++nt)
            #pragma unroll
            for (int reg = 0; reg < 4; ++reg) {
                int mm = m0 + 16 * w + q * 4 + reg;     // C/D row map
                int nn = 16 * nt + r;                   // C/D col map
                dst[(size_t)mm * H_ + nn] = f2bf(acc[nt][reg]);
            }
    }
}

// ---------------------------------------------------------------------------
// Kernel B1 (MFMA, stats only — S is NEVER materialized): per-128-row-chunk
// column stats (pm,pl) straight from the QK^T accumulators.  MFMA sequence
// (kk=0..3 accumulate) matches out_kernel's recompute -> bitwise-identical
// scores, so exp(v - m) <= 1 is guaranteed there.  Tree-max + independent
// exps in the epilogue.
// ---------------------------------------------------------------------------
__global__ __launch_bounds__(256) void stats_kernel(
    const u16* __restrict__ Qb, const u16* __restrict__ Kb,
    float* __restrict__ pm, float* __restrict__ pl)
{
    const int si = blockIdx.x;                  // 0..31 (s tile, 64 wide)
    const int ti = blockIdx.y;                  // 0..15 (t tile, 128 tall)
    const int b  = blockIdx.z;
    if (si > 2 * ti + 1) return;                // strictly-upper tiles unused
    const int t0 = ti * 128, s0 = si * 64;
    const bool diag = (si >= 2 * ti);           // tile touches the diagonal

    __shared__ u16 smem[128 * 136 + 64 * 136];  // 52.2 KB: Qs | Ks, then reused
    u16* Qs = smem;
    u16* Ks = smem + 128 * 136;

    const u16* Qg = Qb + ((size_t)b * T_ + t0) * H_;
    const u16* Kg = Kb + ((size_t)b * T_ + s0) * H_;

    for (int i = threadIdx.x; i < 128 * 16; i += 256) {
        int rr = i >> 4, c = i & 15;
        *(float4*)&Qs[rr * 136 + c * 8] = *(const float4*)&Qg[(size_t)rr * H_ + c * 8];
    }
    for (int i = threadIdx.x; i < 64 * 16; i += 256) {
        int rr = i >> 4, c = i & 15;
        *(float4*)&Ks[rr * 136 + c * 8] = *(const float4*)&Kg[(size_t)rr * H_ + c * 8];
    }
    __syncthreads();

    const int w    = threadIdx.x >> 6;          // wave -> t rows [32w,32w+32)
    const int lane = threadIdx.x & 63;
    const int q    = lane >> 4, r = lane & 15;

    floatx4 acc[2][4] = {};
    #pragma unroll
    for (int kk = 0; kk < 4; ++kk) {
        short8 a0 = *(const short8*)&Qs[(32 * w +      r) * 136 + kk * 32 + q * 8];
        short8 a1 = *(const short8*)&Qs[(32 * w + 16 + r) * 136 + kk * 32 + q * 8];
        #pragma unroll
        for (int nt = 0; nt < 4; ++nt) {
            short8 bf = *(const short8*)&Ks[(16 * nt + r) * 136 + kk * 32 + q * 8];
            acc[0][nt] = __builtin_amdgcn_mfma_f32_16x16x32_bf16(a0, bf, acc[0][nt], 0, 0, 0);
            acc[1][nt] = __builtin_amdgcn_mfma_f32_16x16x32_bf16(a1, bf, acc[1][nt], 0, 0, 0);
        }
    }
    __syncthreads();                            // everyone done with Qs/Ks

    // ---- reuse smem for stats reduction arrays --------------------------
    float* redm = (float*)smem;                 // [16][64]
    float* redl = redm + 16 * 64;               // [16][64]

    const float scale = 0.08838834764831845f;   // 1/sqrt(128)
    #pragma unroll
    for (int nt = 0; nt < 4; ++nt) {
        const int s = s0 + 16 * nt + r;
        float v[8];  bool val[8];
        #pragma unroll
        for (int mt = 0; mt < 2; ++mt)
            #pragma unroll
            for (int reg = 0; reg < 4; ++reg) {
                const int j  = mt * 4 + reg;
                const int tl = 32 * w + 16 * mt + q * 4 + reg;
                v[j] = acc[mt][nt][reg] * scale;
                val[j] = (!diag) || ((t0 + tl) >= s);
            }
        float mx = -INFINITY;                   // tree max, independent ops
        #pragma unroll
        for (int j = 0; j < 8; ++j) mx = fmaxf(mx, val[j] ? v[j] : -INFINITY);
        float sm = 0.f;                         // 8 independent exps
        #pragma unroll
        for (int j = 0; j < 8; ++j) if (val[j]) sm += __expf(v[j] - mx);
        redm[(4 * w + q) * 64 + 16 * nt + r] = mx;
        redl[(4 * w + q) * 64 + 16 * nt + r] = sm;
    }
    __syncthreads();

    if (threadIdx.x < 64) {                     // combine 16 row-groups/col
        const int c = threadIdx.x;
        float M = -INFINITY;
        #pragma unroll
        for (int g = 0; g < 16; ++g) M = fmaxf(M, redm[g * 64 + c]);
        float L = 0.f;
        #pragma unroll
        for (int g = 0; g < 16; ++g) {
            float lg = redl[g * 64 + c];
            if (lg > 0.f) L += lg * __expf(redm[g * 64 + c] - M);
        }
        const size_t o = ((size_t)b * NCHUNK + ti) * T_ + s0 + c;
        pm[o] = M;
        pl[o] = L;
    }
}

// ---------------------------------------------------------------------------
// Kernel B2: combine chunk partials (chunks c >= s>>7 exist); stores 1/L.
// ---------------------------------------------------------------------------
__global__ __launch_bounds__(256) void stats_reduce_kernel(
    const float* __restrict__ pm, const float* __restrict__ pl,
    float* __restrict__ m, float* __restrict__ linv)
{
    const int idx = blockIdx.x * 256 + threadIdx.x;   // b*T + s
    const int b = idx >> 11, s = idx & (T_ - 1);
    const int c0 = s >> 7;                            // first chunk with t>=s

    float M = -INFINITY;
    for (int c = c0; c < NCHUNK; ++c)
        M = fmaxf(M, pm[((size_t)b * NCHUNK + c) * T_ + s]);

    float L = 0.f;
    for (int c = c0; c < NCHUNK; ++c) {
        float mc = pm[((size_t)b * NCHUNK + c) * T_ + s];
        float lc = pl[((size_t)b * NCHUNK + c) * T_ + s];
        if (lc > 0.f) L += lc * __expf(mc - M);
    }
    m[idx]    = M;
    linv[idx] = 1.0f / L;
}

// ---------------------------------------------------------------------------
// Kernel B3 (MFMA, fused recompute, BARRIER-FREE main loop): out = P @ V
// with S recomputed on the fly.  Block = 512 thr = 8 waves, one 16-row
// t-tile; wave w handles s-chunks ci ≡ w (mod 8); heavy tiles first.
//   - Q A-frags preloaded once into registers straight from global.
//   - K / V B-frags read directly from global (16B/lane, L2-resident).
//   - P transposed C/D->A via a WAVE-LOCAL LDS patch (overlaid on the
//     reduction buffer; only intra-wave lgkmcnt ordering, no barriers).
//   - mask only on each tile's final chunk (all earlier chunks have s<t0).
// One cross-wave LDS reduction at the end.
// ---------------------------------------------------------------------------
__global__ __launch_bounds__(512) void out_kernel(
    const u16* __restrict__ Qb, const u16* __restrict__ Kb,
    const u16* __restrict__ Vt,
    const float* __restrict__ m, const float* __restrict__ linv,
    float* __restrict__ out)
{
    const int b  = blockIdx.y;
    const int tb = (int)(gridDim.x - 1 - blockIdx.x); // heavy tiles first
    const int t0 = tb * 16;
    const int nchunks = (t0 + 79) >> 6;               // = t0/64 + 1

    const int w    = threadIdx.x >> 6;                // 0..7: chunk split
    const int lane = threadIdx.x & 63;
    const int q    = lane >> 4, r = lane & 15;

    __shared__ float red[8][16 * 128];                // 64 KB (Ps overlaid)
    u16* Psw = ((u16*)red) + w * (16 * 72);           // wave-local 16x72 bf16

    // Q A-fragments: Q[t0+r][kk*32+q*8 ..+7], loaded once, reused all chunks
    const u16* Qg = Qb + ((size_t)b * T_ + t0) * H_;
    short8 qf[4];
    #pragma unroll
    for (int kk = 0; kk < 4; ++kk)
        qf[kk] = *(const short8*)&Qg[(size_t)r * H_ + kk * 32 + q * 8];

    const u16*   KbB = Kb   + (size_t)b * T_ * H_;
    const u16*   VtB = Vt   + (size_t)b * H_ * T_;
    const float* mB  = m    + (size_t)b * T_;
    const float* lB  = linv + (size_t)b * T_;
    const float scale = 0.08838834764831845f;         // 1/sqrt(128)

    floatx4 acc[8] = {};                              // 16(t) x 128(h)

    for (int ci = w; ci < nchunks; ci += 8) {
        const int s0 = ci * 64;

        // QK^T: 16 t-rows x 64 s-cols; K B-frags straight from global
        floatx4 as[4] = {};
        #pragma unroll
        for (int kk = 0; kk < 4; ++kk)
            #pragma unroll
            for (int nt = 0; nt < 4; ++nt) {
                short8 bf = *(const short8*)
                    &KbB[(size_t)(s0 + 16 * nt + r) * H_ + kk * 32 + q * 8];
                as[nt] = __builtin_amdgcn_mfma_f32_16x16x32_bf16(qf[kk], bf, as[nt], 0, 0, 0);
            }

        // normalize -> P (bf16) into this wave's own LDS patch
        const bool last = (ci == nchunks - 1);        // only chunk with s>t
        #pragma unroll
        for (int nt = 0; nt < 4; ++nt) {
            const int s  = s0 + 16 * nt + r;          // C/D col map
            const float mm = mB[s];
            const float ll = lB[s];
            #pragma unroll
            for (int reg = 0; reg < 4; ++reg) {
                const int tl = q * 4 + reg;           // C/D row map (local t)
                float p = 0.f;
                if (!last || s <= t0 + tl)
                    p = __expf(as[nt][reg] * scale - mm) * ll;
                Psw[tl * 72 + 16 * nt + r] = f2bf(p);
            }
        }
        // intra-wave LDS write->read ordering only (compiler lgkmcnt)

        // PV: A from own Ps patch, B straight from global Vt
        #pragma unroll
        for (int kk2 = 0; kk2 < 2; ++kk2) {
            short8 af = *(const short8*)&Psw[r * 72 + kk2 * 32 + q * 8];
            #pragma unroll
            for (int nt = 0; nt < 8; ++nt) {
                short8 bf = *(const short8*)
                    &VtB[(size_t)(16 * nt + r) * T_ + s0 + kk2 * 32 + q * 8];
                acc[nt] = __builtin_amdgcn_mfma_f32_16x16x32_bf16(af, bf, acc[nt], 0, 0, 0);
            }
        }
    }

    __syncthreads();                                  // all waves done w/ Ps
    #pragma unroll
    for (int nt = 0; nt < 8; ++nt)
        #pragma unroll
        for (int reg = 0; reg < 4; ++reg)
            red[w][(q * 4 + reg) * 128 + 16 * nt + r] = acc[nt][reg];
    __syncthreads();

    float* outB = out + ((size_t)b * T_ + t0) * H_;
    for (int i = threadIdx.x; i < 16 * 128; i += 512) {
        float sum = 0.f;
        #pragma unroll
        for (int g = 0; g < 8; ++g) sum += red[g][i];
        outB[i] = sum;
    }
}

// ---------------------------------------------------------------------------
extern "C" void kernel_launch(void* const* d_in, const int* in_sizes, int n_in,
                              void* d_out, int out_size, void* d_ws, size_t ws_size,
                              hipStream_t stream) {
    const float* x  = (const float*)d_in[0];
    const float* Wq = (const float*)d_in[1];
    const float* Wk = (const float*)d_in[2];
    const float* Wv = (const float*)d_in[3];
    float* out = (float*)d_out;

    // workspace: m, linv fp32 [B*T]; Wt bf16 [3*H*C]; Qb,Kb [B*T*H]; Vt [B*H*T]
    float* m    = (float*)d_ws;
    float* linv = m + (size_t)B_ * T_;
    u16*   Wt   = (u16*)(linv + (size_t)B_ * T_);      // 0.75 MB
    u16*   Qb   = Wt + (size_t)3 * H_ * C_;            // 2 MB
    u16*   Kb   = Qb + (size_t)B_ * T_ * H_;           // 2 MB
    u16*   Vt   = Kb + (size_t)B_ * T_ * H_;           // 2 MB
    // total ~7 MB

    // d_out staging: pm/pl (1 MB) written by stats, read by stats_reduce,
    // then out_kernel overwrites all 4 MB.
    float* pm = (float*)d_out;
    float* pl = pm + (size_t)B_ * NCHUNK * T_;

    convert_w_kernel  <<<dim3(C_ / 64, H_ / 64, 3),    dim3(256), 0, stream>>>(Wq, Wk, Wv, Wt);
    qkv_gemm_kernel   <<<dim3(B_ * T_ / 64, 3),        dim3(256), 0, stream>>>(x, Wt, Qb, Kb, Vt);
    stats_kernel      <<<dim3(32, 16, B_),             dim3(256), 0, stream>>>(Qb, Kb, pm, pl);
    stats_reduce_kernel<<<dim3(B_ * T_ / 256),         dim3(256), 0, stream>>>(pm, pl, m, linv);
    out_kernel        <<<dim3(T_ / 16, B_),            dim3(512), 0, stream>>>(Qb, Kb, Vt, m, linv, out);
}

// Round 11
// 171.867 us; speedup vs baseline: 1.1178x; 1.1178x over previous
//
#include <hip/hip_runtime.h>
#include <math.h>

#define B_ 4
#define T_ 2048
#define C_ 1024
#define H_ 128
#define RCHUNK 128                 // rows per stats chunk == scores t-tile
#define NCHUNK (T_ / RCHUNK)       // 16 chunks
#define NSCH 32                    // number of 64-wide s-chunks (T/64)

typedef unsigned short u16;
typedef unsigned int   u32;
typedef short short8  __attribute__((ext_vector_type(8)));  // 8 bf16 = 4 VGPRs
typedef short short4v __attribute__((ext_vector_type(4)));  // 8B
typedef float floatx4 __attribute__((ext_vector_type(4)));  // MFMA C/D

// fp32 -> bf16 round-to-nearest-even
__device__ __forceinline__ u16 f2bf(float f) {
    union { float f; u32 u; } v; v.f = f;
    return (u16)((v.u + 0x7fffu + ((v.u >> 16) & 1u)) >> 16);
}
// bf16 -> fp32
__device__ __forceinline__ float bf2f(u16 h) {
    union { u32 u; float f; } v; v.u = ((u32)h) << 16;
    return v.f;
}

// ---------------------------------------------------------------------------
// Kernel A1: W [C][H] fp32 -> Wt [3][H][C] bf16 (transposed for MFMA B-frags).
// ---------------------------------------------------------------------------
__global__ __launch_bounds__(256) void convert_w_kernel(
    const float* __restrict__ Wq, const float* __restrict__ Wk,
    const float* __restrict__ Wv, u16* __restrict__ Wt)
{
    const int k0 = blockIdx.x * 64, n0 = blockIdx.y * 64, widx = blockIdx.z;
    const float* W = (widx == 0) ? Wq : (widx == 1) ? Wk : Wv;

    __shared__ float ts[64][68];                // +4 pad
    for (int i = threadIdx.x; i < 64 * 16; i += 256) {
        int r = i >> 4, c4 = i & 15;
        float4 v = *(const float4*)&W[(size_t)(k0 + r) * H_ + n0 + c4 * 4];
        ts[r][c4 * 4 + 0] = v.x; ts[r][c4 * 4 + 1] = v.y;
        ts[r][c4 * 4 + 2] = v.z; ts[r][c4 * 4 + 3] = v.w;
    }
    __syncthreads();
    for (int i = threadIdx.x; i < 64 * 16; i += 256) {
        int n = i >> 4, k4 = i & 15;
        short4v o;
        #pragma unroll
        for (int j = 0; j < 4; ++j) o[j] = (short)f2bf(ts[k4 * 4 + j][n]);
        *(short4v*)&Wt[(size_t)widx * H_ * C_ + (size_t)(n0 + n) * C_ + k0 + k4 * 4] = o;
    }
}

// ---------------------------------------------------------------------------
// Kernel A2 (MFMA): QKV projection, A staged straight from fp32 x with
// in-register bf16 conversion.  grid (M/64, 3); block 256 = 4 waves;
// tile 64(m) x 128(n); BK=128.  widx 0/1 -> Q,K row-major; widx 2 -> V
// stored TRANSPOSED directly (C/D gives 4 consecutive t per lane).
// ---------------------------------------------------------------------------
__global__ __launch_bounds__(256) void qkv_gemm_kernel(
    const float* __restrict__ x, const u16* __restrict__ Wt,
    u16* __restrict__ Qb, u16* __restrict__ Kb, u16* __restrict__ Vt)
{
    const int m0   = blockIdx.x * 64;
    const int widx = blockIdx.y;
    const u16* Wg = Wt + (size_t)widx * H_ * C_;

    __shared__ u16 As[64 * 136];                // 17.4 KB
    __shared__ u16 Bs[128 * 136];               // 34.8 KB

    const int w    = threadIdx.x >> 6;          // wave -> m rows [16w,16w+16)
    const int lane = threadIdx.x & 63;
    const int q    = lane >> 4, r = lane & 15;

    floatx4 acc[8] = {};                        // 16(m) x 128(n)

    for (int k0 = 0; k0 < C_; k0 += 128) {
        for (int i = threadIdx.x; i < 64 * 16; i += 256) {
            int rr = i >> 4, c = i & 15;
            const float* xg = &x[(size_t)(m0 + rr) * C_ + k0 + c * 8];
            float4 a = *(const float4*)xg;
            float4 b = *(const float4*)(xg + 4);
            short8 o;
            o[0]=(short)f2bf(a.x); o[1]=(short)f2bf(a.y);
            o[2]=(short)f2bf(a.z); o[3]=(short)f2bf(a.w);
            o[4]=(short)f2bf(b.x); o[5]=(short)f2bf(b.y);
            o[6]=(short)f2bf(b.z); o[7]=(short)f2bf(b.w);
            *(short8*)&As[rr * 136 + c * 8] = o;
        }
        for (int i = threadIdx.x; i < 128 * 16; i += 256) {
            int rr = i >> 4, c = i & 15;
            *(float4*)&Bs[rr * 136 + c * 8] =
                *(const float4*)&Wg[(size_t)rr * C_ + k0 + c * 8];
        }
        __syncthreads();

        #pragma unroll
        for (int kk = 0; kk < 4; ++kk) {
            short8 af = *(const short8*)&As[(16 * w + r) * 136 + kk * 32 + q * 8];
            #pragma unroll
            for (int nt = 0; nt < 8; ++nt) {
                short8 bf = *(const short8*)&Bs[(16 * nt + r) * 136 + kk * 32 + q * 8];
                acc[nt] = __builtin_amdgcn_mfma_f32_16x16x32_bf16(af, bf, acc[nt], 0, 0, 0);
            }
        }
        __syncthreads();
    }

    if (widx == 2) {
        const int bb  = m0 / T_;                // 64-row tile never spans b
        const int tt0 = (m0 - bb * T_) + 16 * w + q * 4;
        #pragma unroll
        for (int nt = 0; nt < 8; ++nt) {
            short4v o;
            #pragma unroll
            for (int reg = 0; reg < 4; ++reg) o[reg] = (short)f2bf(acc[nt][reg]);
            *(short4v*)&Vt[((size_t)bb * H_ + 16 * nt + r) * T_ + tt0] = o;
        }
    } else {
        u16* dst = (widx == 0) ? Qb : Kb;
        #pragma unroll
        for (int nt = 0; nt < 8; ++nt)
            #pragma unroll
            for (int reg = 0; reg < 4; ++reg) {
                int mm = m0 + 16 * w + q * 4 + reg;     // C/D row map
                int nn = 16 * nt + r;                   // C/D col map
                dst[(size_t)mm * H_ + nn] = f2bf(acc[nt][reg]);
            }
    }
}

// ---------------------------------------------------------------------------
// Kernel B1 (MFMA, fused stats): S tile = scale * Q·K^T (lower triangle),
// written as BF16 in CHUNK-TILED layout S3[b][si][t][64] — the 128x64 tile
// is one contiguous 16 KB streaming store.  PLUS per-128-row-chunk column
// stats (pm,pl) from the accumulators (tree-max + independent exps).
// ---------------------------------------------------------------------------
__global__ __launch_bounds__(256) void scores_kernel(
    const u16* __restrict__ Qb, const u16* __restrict__ Kb,
    u16* __restrict__ S, float* __restrict__ pm, float* __restrict__ pl)
{
    const int si = blockIdx.x;                  // 0..31 (s tile, 64 wide)
    const int ti = blockIdx.y;                  // 0..15 (t tile, 128 tall)
    const int b  = blockIdx.z;
    if (si > 2 * ti + 1) return;                // strictly-upper tiles unused
    const int t0 = ti * 128, s0 = si * 64;
    const bool diag = (si >= 2 * ti);           // tile touches the diagonal

    __shared__ u16 smem[128 * 136 + 64 * 136];  // 52.2 KB: Qs | Ks, then reused
    u16* Qs = smem;
    u16* Ks = smem + 128 * 136;

    const u16* Qg = Qb + ((size_t)b * T_ + t0) * H_;
    const u16* Kg = Kb + ((size_t)b * T_ + s0) * H_;

    for (int i = threadIdx.x; i < 128 * 16; i += 256) {
        int rr = i >> 4, c = i & 15;
        *(float4*)&Qs[rr * 136 + c * 8] = *(const float4*)&Qg[(size_t)rr * H_ + c * 8];
    }
    for (int i = threadIdx.x; i < 64 * 16; i += 256) {
        int rr = i >> 4, c = i & 15;
        *(float4*)&Ks[rr * 136 + c * 8] = *(const float4*)&Kg[(size_t)rr * H_ + c * 8];
    }
    __syncthreads();

    const int w    = threadIdx.x >> 6;          // wave -> t rows [32w,32w+32)
    const int lane = threadIdx.x & 63;
    const int q    = lane >> 4, r = lane & 15;

    floatx4 acc[2][4] = {};
    #pragma unroll
    for (int kk = 0; kk < 4; ++kk) {
        short8 a0 = *(const short8*)&Qs[(32 * w +      r) * 136 + kk * 32 + q * 8];
        short8 a1 = *(const short8*)&Qs[(32 * w + 16 + r) * 136 + kk * 32 + q * 8];
        #pragma unroll
        for (int nt = 0; nt < 4; ++nt) {
            short8 bf = *(const short8*)&Ks[(16 * nt + r) * 136 + kk * 32 + q * 8];
            acc[0][nt] = __builtin_amdgcn_mfma_f32_16x16x32_bf16(a0, bf, acc[0][nt], 0, 0, 0);
            acc[1][nt] = __builtin_amdgcn_mfma_f32_16x16x32_bf16(a1, bf, acc[1][nt], 0, 0, 0);
        }
    }
    __syncthreads();                            // everyone done with Qs/Ks

    // ---- reuse smem: bf16 tile [128][72] + stats red arrays -------------
    u16*   tile = smem;                         // 18.4 KB
    float* redm = (float*)(smem + 128 * 72);    // [16][64]
    float* redl = redm + 16 * 64;               // [16][64]

    const float scale = 0.08838834764831845f;   // 1/sqrt(128)
    #pragma unroll
    for (int nt = 0; nt < 4; ++nt) {
        const int s = s0 + 16 * nt + r;
        float v[8];  bool val[8];
        #pragma unroll
        for (int mt = 0; mt < 2; ++mt)
            #pragma unroll
            for (int reg = 0; reg < 4; ++reg) {
                const int j  = mt * 4 + reg;
                const int tl = 32 * w + 16 * mt + q * 4 + reg;
                v[j] = acc[mt][nt][reg] * scale;
                tile[tl * 72 + 16 * nt + r] = f2bf(v[j]);
                val[j] = (!diag) || ((t0 + tl) >= s);
            }
        float mx = -INFINITY;                   // tree max, independent ops
        #pragma unroll
        for (int j = 0; j < 8; ++j) mx = fmaxf(mx, val[j] ? v[j] : -INFINITY);
        float sm = 0.f;                         // 8 independent exps
        #pragma unroll
        for (int j = 0; j < 8; ++j) if (val[j]) sm += __expf(v[j] - mx);
        redm[(4 * w + q) * 64 + 16 * nt + r] = mx;
        redl[(4 * w + q) * 64 + 16 * nt + r] = sm;
    }
    __syncthreads();

    if (threadIdx.x < 64) {                     // combine 16 row-groups/col
        const int c = threadIdx.x;
        float M = -INFINITY;
        #pragma unroll
        for (int g = 0; g < 16; ++g) M = fmaxf(M, redm[g * 64 + c]);
        float L = 0.f;
        #pragma unroll
        for (int g = 0; g < 16; ++g) {
            float lg = redl[g * 64 + c];
            if (lg > 0.f) L += lg * __expf(redm[g * 64 + c] - M);
        }
        const size_t o = ((size_t)b * NCHUNK + ti) * T_ + s0 + c;
        pm[o] = M;
        pl[o] = L;
    }

    // contiguous 16 KB tile store: S3[b][si][t0..t0+128)[0..64)
    u16* Sg = S + (((size_t)b * NSCH + si) * T_ + t0) * 64;
    for (int i = threadIdx.x; i < 128 * 8; i += 256) {
        int tl = i >> 3, c8 = i & 7;
        *(float4*)&Sg[(size_t)i * 8] = *(float4*)&tile[tl * 72 + c8 * 8];
    }
}

// ---------------------------------------------------------------------------
// Kernel B2: combine chunk partials (chunks c >= s>>7 exist); stores 1/L.
// ---------------------------------------------------------------------------
__global__ __launch_bounds__(256) void stats_reduce_kernel(
    const float* __restrict__ pm, const float* __restrict__ pl,
    float* __restrict__ m, float* __restrict__ linv)
{
    const int idx = blockIdx.x * 256 + threadIdx.x;   // b*T + s
    const int b = idx >> 11, s = idx & (T_ - 1);
    const int c0 = s >> 7;                            // first chunk with t>=s

    float M = -INFINITY;
    for (int c = c0; c < NCHUNK; ++c)
        M = fmaxf(M, pm[((size_t)b * NCHUNK + c) * T_ + s]);

    float L = 0.f;
    for (int c = c0; c < NCHUNK; ++c) {
        float mc = pm[((size_t)b * NCHUNK + c) * T_ + s];
        float lc = pl[((size_t)b * NCHUNK + c) * T_ + s];
        if (lc > 0.f) L += lc * __expf(mc - M);
    }
    m[idx]    = M;
    linv[idx] = 1.0f / L;
}

// ---------------------------------------------------------------------------
// Kernel B3 (MFMA, register-resident, pipelined, 8-way split-s): out = P @ V,
// P = exp(S-m[s])*linv[s], masked s <= t.  S in chunk-tiled layout: each
// wave's per-chunk read is a contiguous 2 KB block (16 rows x 128 B).
// Block = 512 thr = 8 waves, one 16-row t-tile; wave w handles chunks
// ci ≡ w (mod 8); ci+8 prefetched into registers while ci computes.
// Padded (stride-132) LDS reduction to avoid 4-way bank conflicts.
// ---------------------------------------------------------------------------
#define RST 132
__global__ __launch_bounds__(512) void out_kernel(
    const u16* __restrict__ S, const u16* __restrict__ Vt,
    const float* __restrict__ m, const float* __restrict__ linv,
    float* __restrict__ out)
{
    const int b  = blockIdx.y;
    const int tb = (int)(gridDim.x - 1 - blockIdx.x); // heavy tiles first
    const int t0 = tb * 16;
    const int nchunks = (t0 + 79) >> 6;               // s0 <= t0+15

    const int w    = threadIdx.x >> 6;                // 0..7: chunk split
    const int lane = threadIdx.x & 63;
    const int q    = lane >> 4, r = lane & 15;
    const int t    = t0 + r;                          // this lane's A row

    const u16*   SB  = S    + (size_t)b * NSCH * T_ * 64;
    const float* mB  = m    + (size_t)b * T_;
    const float* lB  = linv + (size_t)b * T_;
    const u16*   VtB = Vt   + (size_t)b * H_ * T_;

    floatx4 acc[8] = {};

    // prefetch registers for one chunk: S (2x short8), m/linv (8x float4)
    short8 sc[2];  float4 mc[2][2], lc[2][2];

    int ci = w;
    if (ci < nchunks) {
        const u16* Sc = SB + ((size_t)ci * T_ + t) * 64;
        const int  s0 = ci * 64;
        #pragma unroll
        for (int kk = 0; kk < 2; ++kk) {
            const int sl = kk * 32 + q * 8;
            sc[kk]    = *(const short8*)&Sc[sl];
            mc[kk][0] = *(const float4*)&mB[s0 + sl];
            mc[kk][1] = *(const float4*)&mB[s0 + sl + 4];
            lc[kk][0] = *(const float4*)&lB[s0 + sl];
            lc[kk][1] = *(const float4*)&lB[s0 + sl + 4];
        }
    }

    while (ci < nchunks) {
        const int s0 = ci * 64;
        const int cn = ci + 8;

        short8 sn[2];  float4 mn[2][2], ln[2][2];
        if (cn < nchunks) {                           // issue next-chunk loads
            const u16* Sc = SB + ((size_t)cn * T_ + t) * 64;
            const int  s0n = cn * 64;
            #pragma unroll
            for (int kk = 0; kk < 2; ++kk) {
                const int sl = kk * 32 + q * 8;
                sn[kk]    = *(const short8*)&Sc[sl];
                mn[kk][0] = *(const float4*)&mB[s0n + sl];
                mn[kk][1] = *(const float4*)&mB[s0n + sl + 4];
                ln[kk][0] = *(const float4*)&lB[s0n + sl];
                ln[kk][1] = *(const float4*)&lB[s0n + sl + 4];
            }
        }

        #pragma unroll
        for (int kk = 0; kk < 2; ++kk) {
            const int sb = s0 + kk * 32 + q * 8;      // global s base
            float mv[8], lv[8];
            *(float4*)&mv[0] = mc[kk][0];  *(float4*)&mv[4] = mc[kk][1];
            *(float4*)&lv[0] = lc[kk][0];  *(float4*)&lv[4] = lc[kk][1];

            short8 af;
            #pragma unroll
            for (int j = 0; j < 8; ++j) {
                float wj = 0.f;
                if (sb + j <= t)
                    wj = __expf(bf2f((u16)sc[kk][j]) - mv[j]) * lv[j];
                af[j] = (short)f2bf(wj);
            }
            #pragma unroll
            for (int nt = 0; nt < 8; ++nt) {
                short8 bf = *(const short8*)&VtB[(size_t)(16 * nt + r) * T_ + sb];
                acc[nt] = __builtin_amdgcn_mfma_f32_16x16x32_bf16(af, bf, acc[nt], 0, 0, 0);
            }
        }

        #pragma unroll
        for (int kk = 0; kk < 2; ++kk) {              // rotate pipeline regs
            sc[kk] = sn[kk];
            mc[kk][0] = mn[kk][0];  mc[kk][1] = mn[kk][1];
            lc[kk][0] = ln[kk][0];  lc[kk][1] = ln[kk][1];
        }
        ci = cn;
    }

    __shared__ float red[8][16 * RST];                // 67.6 KB, padded rows
    #pragma unroll
    for (int nt = 0; nt < 8; ++nt)
        #pragma unroll
        for (int reg = 0; reg < 4; ++reg)
            red[w][(q * 4 + reg) * RST + 16 * nt + r] = acc[nt][reg];
    __syncthreads();

    float* outB = out + ((size_t)b * T_ + t0) * H_;
    for (int i = threadIdx.x; i < 16 * 128; i += 512) {
        const int row = i >> 7, col = i & 127;
        float sum = 0.f;
        #pragma unroll
        for (int g = 0; g < 8; ++g) sum += red[g][row * RST + col];
        outB[i] = sum;
    }
}

// ---------------------------------------------------------------------------
extern "C" void kernel_launch(void* const* d_in, const int* in_sizes, int n_in,
                              void* d_out, int out_size, void* d_ws, size_t ws_size,
                              hipStream_t stream) {
    const float* x  = (const float*)d_in[0];
    const float* Wq = (const float*)d_in[1];
    const float* Wk = (const float*)d_in[2];
    const float* Wv = (const float*)d_in[3];
    float* out = (float*)d_out;

    // workspace: S3 bf16 [B][32][T][64] (32 MB), m, linv, Wt, Qb, Kb, Vt.
    u16*   S    = (u16*)d_ws;                          // 32 MB
    float* m    = (float*)(S + (size_t)B_ * T_ * T_);
    float* linv = m + (size_t)B_ * T_;
    u16*   Wt   = (u16*)(linv + (size_t)B_ * T_);      // 0.75 MB
    u16*   Qb   = Wt + (size_t)3 * H_ * C_;            // 2 MB
    u16*   Kb   = Qb + (size_t)B_ * T_ * H_;           // 2 MB
    u16*   Vt   = Kb + (size_t)B_ * T_ * H_;           // 2 MB
    // total ~39 MB

    // d_out staging: pm/pl (1 MB) written by scores, read by stats_reduce,
    // then out_kernel overwrites all 4 MB.
    float* pm = (float*)d_out;
    float* pl = pm + (size_t)B_ * NCHUNK * T_;

    convert_w_kernel  <<<dim3(C_ / 64, H_ / 64, 3),    dim3(256), 0, stream>>>(Wq, Wk, Wv, Wt);
    qkv_gemm_kernel   <<<dim3(B_ * T_ / 64, 3),        dim3(256), 0, stream>>>(x, Wt, Qb, Kb, Vt);
    scores_kernel     <<<dim3(32, 16, B_),             dim3(256), 0, stream>>>(Qb, Kb, S, pm, pl);
    stats_reduce_kernel<<<dim3(B_ * T_ / 256),         dim3(256), 0, stream>>>(pm, pl, m, linv);
    out_kernel        <<<dim3(T_ / 16, B_),            dim3(512), 0, stream>>>(S, Vt, m, linv, out);
}

// Round 12
// 169.908 us; speedup vs baseline: 1.1307x; 1.0115x over previous
//
#include <hip/hip_runtime.h>
#include <math.h>

#define B_ 4
#define T_ 2048
#define C_ 1024
#define H_ 128
#define RCHUNK 128                 // rows per stats chunk == scores t-tile
#define NCHUNK (T_ / RCHUNK)       // 16 chunks
#define NSCH 32                    // number of 64-wide s-chunks (T/64)

typedef unsigned short u16;
typedef unsigned int   u32;
typedef short short8  __attribute__((ext_vector_type(8)));  // 8 bf16 = 4 VGPRs
typedef short short4v __attribute__((ext_vector_type(4)));  // 8B
typedef float floatx4 __attribute__((ext_vector_type(4)));  // MFMA C/D

// fp32 -> bf16 round-to-nearest-even
__device__ __forceinline__ u16 f2bf(float f) {
    union { float f; u32 u; } v; v.f = f;
    return (u16)((v.u + 0x7fffu + ((v.u >> 16) & 1u)) >> 16);
}
// bf16 -> fp32
__device__ __forceinline__ float bf2f(u16 h) {
    union { u32 u; float f; } v; v.u = ((u32)h) << 16;
    return v.f;
}

// ---------------------------------------------------------------------------
// Kernel A1: W [C][H] fp32 -> Wt [3][H][C] bf16 (transposed for MFMA B-frags).
// ---------------------------------------------------------------------------
__global__ __launch_bounds__(256) void convert_w_kernel(
    const float* __restrict__ Wq, const float* __restrict__ Wk,
    const float* __restrict__ Wv, u16* __restrict__ Wt)
{
    const int k0 = blockIdx.x * 64, n0 = blockIdx.y * 64, widx = blockIdx.z;
    const float* W = (widx == 0) ? Wq : (widx == 1) ? Wk : Wv;

    __shared__ float ts[64][68];                // +4 pad
    for (int i = threadIdx.x; i < 64 * 16; i += 256) {
        int r = i >> 4, c4 = i & 15;
        float4 v = *(const float4*)&W[(size_t)(k0 + r) * H_ + n0 + c4 * 4];
        ts[r][c4 * 4 + 0] = v.x; ts[r][c4 * 4 + 1] = v.y;
        ts[r][c4 * 4 + 2] = v.z; ts[r][c4 * 4 + 3] = v.w;
    }
    __syncthreads();
    for (int i = threadIdx.x; i < 64 * 16; i += 256) {
        int n = i >> 4, k4 = i & 15;
        short4v o;
        #pragma unroll
        for (int j = 0; j < 4; ++j) o[j] = (short)f2bf(ts[k4 * 4 + j][n]);
        *(short4v*)&Wt[(size_t)widx * H_ * C_ + (size_t)(n0 + n) * C_ + k0 + k4 * 4] = o;
    }
}

// ---------------------------------------------------------------------------
// Kernel A2 (MFMA): QKV projection, A staged straight from fp32 x with
// in-register bf16 conversion.  grid (M/64, 3); block 256 = 4 waves;
// tile 64(m) x 128(n); BK=128.  widx 0/1 -> Q,K row-major; widx 2 -> V
// stored TRANSPOSED directly (C/D gives 4 consecutive t per lane).
// ---------------------------------------------------------------------------
__global__ __launch_bounds__(256) void qkv_gemm_kernel(
    const float* __restrict__ x, const u16* __restrict__ Wt,
    u16* __restrict__ Qb, u16* __restrict__ Kb, u16* __restrict__ Vt)
{
    const int m0   = blockIdx.x * 64;
    const int widx = blockIdx.y;
    const u16* Wg = Wt + (size_t)widx * H_ * C_;

    __shared__ u16 As[64 * 136];                // 17.4 KB
    __shared__ u16 Bs[128 * 136];               // 34.8 KB

    const int w    = threadIdx.x >> 6;          // wave -> m rows [16w,16w+16)
    const int lane = threadIdx.x & 63;
    const int q    = lane >> 4, r = lane & 15;

    floatx4 acc[8] = {};                        // 16(m) x 128(n)

    for (int k0 = 0; k0 < C_; k0 += 128) {
        for (int i = threadIdx.x; i < 64 * 16; i += 256) {
            int rr = i >> 4, c = i & 15;
            const float* xg = &x[(size_t)(m0 + rr) * C_ + k0 + c * 8];
            float4 a = *(const float4*)xg;
            float4 b = *(const float4*)(xg + 4);
            short8 o;
            o[0]=(short)f2bf(a.x); o[1]=(short)f2bf(a.y);
            o[2]=(short)f2bf(a.z); o[3]=(short)f2bf(a.w);
            o[4]=(short)f2bf(b.x); o[5]=(short)f2bf(b.y);
            o[6]=(short)f2bf(b.z); o[7]=(short)f2bf(b.w);
            *(short8*)&As[rr * 136 + c * 8] = o;
        }
        for (int i = threadIdx.x; i < 128 * 16; i += 256) {
            int rr = i >> 4, c = i & 15;
            *(float4*)&Bs[rr * 136 + c * 8] =
                *(const float4*)&Wg[(size_t)rr * C_ + k0 + c * 8];
        }
        __syncthreads();

        #pragma unroll
        for (int kk = 0; kk < 4; ++kk) {
            short8 af = *(const short8*)&As[(16 * w + r) * 136 + kk * 32 + q * 8];
            #pragma unroll
            for (int nt = 0; nt < 8; ++nt) {
                short8 bf = *(const short8*)&Bs[(16 * nt + r) * 136 + kk * 32 + q * 8];
                acc[nt] = __builtin_amdgcn_mfma_f32_16x16x32_bf16(af, bf, acc[nt], 0, 0, 0);
            }
        }
        __syncthreads();
    }

    if (widx == 2) {
        const int bb  = m0 / T_;                // 64-row tile never spans b
        const int tt0 = (m0 - bb * T_) + 16 * w + q * 4;
        #pragma unroll
        for (int nt = 0; nt < 8; ++nt) {
            short4v o;
            #pragma unroll
            for (int reg = 0; reg < 4; ++reg) o[reg] = (short)f2bf(acc[nt][reg]);
            *(short4v*)&Vt[((size_t)bb * H_ + 16 * nt + r) * T_ + tt0] = o;
        }
    } else {
        u16* dst = (widx == 0) ? Qb : Kb;
        #pragma unroll
        for (int nt = 0; nt < 8; ++nt)
            #pragma unroll
            for (int reg = 0; reg < 4; ++reg) {
                int mm = m0 + 16 * w + q * 4 + reg;     // C/D row map
                int nn = 16 * nt + r;                   // C/D col map
                dst[(size_t)mm * H_ + nn] = f2bf(acc[nt][reg]);
            }
    }
}

// ---------------------------------------------------------------------------
// Kernel B1 (MFMA, fused stats): 128x128 tile of S = scale * Q·K^T (lower
// triangle), written as BF16 in chunk-tiled layout S3[b][s/64][t][64] (two
// contiguous 16 KB chunk stores), PLUS per-128-row-chunk column stats
// (pm,pl) from the accumulators (tree-max + independent exps).
// 544 blocks (vs 1088 at 128x64): half the staging traffic per MFMA.
// ---------------------------------------------------------------------------
__global__ __launch_bounds__(256) void scores_kernel(
    const u16* __restrict__ Qb, const u16* __restrict__ Kb,
    u16* __restrict__ S, float* __restrict__ pm, float* __restrict__ pl)
{
    const int si = blockIdx.x;                  // 0..15 (s tile, 128 wide)
    const int ti = blockIdx.y;                  // 0..15 (t tile, 128 tall)
    const int b  = blockIdx.z;
    if (si > ti) return;                        // strictly-upper tiles unused
    const int t0 = ti * 128, s0 = si * 128;
    const bool diag = (si == ti);               // tile touches the diagonal

    __shared__ u16 smem[2 * 128 * 136];         // 69.6 KB: Qs | Ks, then reused
    u16* Qs = smem;
    u16* Ks = smem + 128 * 136;

    const u16* Qg = Qb + ((size_t)b * T_ + t0) * H_;
    const u16* Kg = Kb + ((size_t)b * T_ + s0) * H_;

    for (int i = threadIdx.x; i < 128 * 16; i += 256) {
        int rr = i >> 4, c = i & 15;
        *(float4*)&Qs[rr * 136 + c * 8] = *(const float4*)&Qg[(size_t)rr * H_ + c * 8];
        *(float4*)&Ks[rr * 136 + c * 8] = *(const float4*)&Kg[(size_t)rr * H_ + c * 8];
    }
    __syncthreads();

    const int w    = threadIdx.x >> 6;          // wave -> t rows [32w,32w+32)
    const int lane = threadIdx.x & 63;
    const int q    = lane >> 4, r = lane & 15;

    floatx4 acc[2][8] = {};                     // [m-tile][n-tile] 32t x 128s
    #pragma unroll
    for (int kk = 0; kk < 4; ++kk) {
        short8 a0 = *(const short8*)&Qs[(32 * w +      r) * 136 + kk * 32 + q * 8];
        short8 a1 = *(const short8*)&Qs[(32 * w + 16 + r) * 136 + kk * 32 + q * 8];
        #pragma unroll
        for (int nt = 0; nt < 8; ++nt) {
            short8 bf = *(const short8*)&Ks[(16 * nt + r) * 136 + kk * 32 + q * 8];
            acc[0][nt] = __builtin_amdgcn_mfma_f32_16x16x32_bf16(a0, bf, acc[0][nt], 0, 0, 0);
            acc[1][nt] = __builtin_amdgcn_mfma_f32_16x16x32_bf16(a1, bf, acc[1][nt], 0, 0, 0);
        }
    }
    __syncthreads();                            // everyone done with Qs/Ks

    // ---- reuse smem: bf16 tile [128][136] + stats red arrays ------------
    u16*   tile = smem;                         // 34.8 KB
    float* redm = (float*)(smem + 128 * 136);   // [16][128] = 8 KB
    float* redl = redm + 16 * 128;              // [16][128] = 8 KB

    const float scale = 0.08838834764831845f;   // 1/sqrt(128)
    #pragma unroll
    for (int nt = 0; nt < 8; ++nt) {
        const int sl = 16 * nt + r;             // local col (C/D col map)
        float v[8];  bool val[8];
        #pragma unroll
        for (int mt = 0; mt < 2; ++mt)
            #pragma unroll
            for (int reg = 0; reg < 4; ++reg) {
                const int j  = mt * 4 + reg;
                const int tl = 32 * w + 16 * mt + q * 4 + reg;
                v[j] = acc[mt][nt][reg] * scale;
                tile[tl * 136 + sl] = f2bf(v[j]);
                val[j] = (!diag) || (tl >= sl);
            }
        float mx = -INFINITY;                   // tree max, independent ops
        #pragma unroll
        for (int j = 0; j < 8; ++j) mx = fmaxf(mx, val[j] ? v[j] : -INFINITY);
        float sm = 0.f;                         // 8 independent exps
        #pragma unroll
        for (int j = 0; j < 8; ++j) if (val[j]) sm += __expf(v[j] - mx);
        redm[(4 * w + q) * 128 + sl] = mx;
        redl[(4 * w + q) * 128 + sl] = sm;
    }
    __syncthreads();

    if (threadIdx.x < 128) {                    // combine 16 row-groups/col
        const int c = threadIdx.x;
        float M = -INFINITY;
        #pragma unroll
        for (int g = 0; g < 16; ++g) M = fmaxf(M, redm[g * 128 + c]);
        float L = 0.f;
        #pragma unroll
        for (int g = 0; g < 16; ++g) {
            float lg = redl[g * 128 + c];
            if (lg > 0.f) L += lg * __expf(redm[g * 128 + c] - M);
        }
        const size_t o = ((size_t)b * NCHUNK + ti) * T_ + s0 + c;
        pm[o] = M;
        pl[o] = L;
    }

    // two contiguous 16 KB chunk stores: S3[b][2si+cc][t0..t0+128)[0..64)
    for (int i = threadIdx.x; i < 128 * 16; i += 256) {
        int tl = i >> 4, cc = (i >> 3) & 1, c8 = i & 7;
        u16* Sg = S + (((size_t)b * NSCH + 2 * si + cc) * T_ + t0 + tl) * 64;
        *(float4*)&Sg[c8 * 8] = *(float4*)&tile[tl * 136 + cc * 64 + c8 * 8];
    }
}

// ---------------------------------------------------------------------------
// Kernel B2: combine chunk partials (chunks c >= s>>7 exist); stores 1/L.
// ---------------------------------------------------------------------------
__global__ __launch_bounds__(256) void stats_reduce_kernel(
    const float* __restrict__ pm, const float* __restrict__ pl,
    float* __restrict__ m, float* __restrict__ linv)
{
    const int idx = blockIdx.x * 256 + threadIdx.x;   // b*T + s
    const int b = idx >> 11, s = idx & (T_ - 1);
    const int c0 = s >> 7;                            // first chunk with t>=s

    float M = -INFINITY;
    for (int c = c0; c < NCHUNK; ++c)
        M = fmaxf(M, pm[((size_t)b * NCHUNK + c) * T_ + s]);

    float L = 0.f;
    for (int c = c0; c < NCHUNK; ++c) {
        float mc = pm[((size_t)b * NCHUNK + c) * T_ + s];
        float lc = pl[((size_t)b * NCHUNK + c) * T_ + s];
        if (lc > 0.f) L += lc * __expf(mc - M);
    }
    m[idx]    = M;
    linv[idx] = 1.0f / L;
}

// ---------------------------------------------------------------------------
// Kernel B3 (MFMA, register-resident, pipelined, 8-way split-s): out = P @ V,
// P = exp(S-m[s])*linv[s], masked s <= t.  S in chunk-tiled layout: each
// wave's per-chunk read is a contiguous 2 KB block (16 rows x 128 B).
// Block = 512 thr = 8 waves, one 16-row t-tile; wave w handles chunks
// ci ≡ w (mod 8); ci+8 prefetched into registers while ci computes.
// Padded (stride-132) LDS reduction to avoid 4-way bank conflicts.
// ---------------------------------------------------------------------------
#define RST 132
__global__ __launch_bounds__(512) void out_kernel(
    const u16* __restrict__ S, const u16* __restrict__ Vt,
    const float* __restrict__ m, const float* __restrict__ linv,
    float* __restrict__ out)
{
    const int b  = blockIdx.y;
    const int tb = (int)(gridDim.x - 1 - blockIdx.x); // heavy tiles first
    const int t0 = tb * 16;
    const int nchunks = (t0 + 79) >> 6;               // s0 <= t0+15

    const int w    = threadIdx.x >> 6;                // 0..7: chunk split
    const int lane = threadIdx.x & 63;
    const int q    = lane >> 4, r = lane & 15;
    const int t    = t0 + r;                          // this lane's A row

    const u16*   SB  = S    + (size_t)b * NSCH * T_ * 64;
    const float* mB  = m    + (size_t)b * T_;
    const float* lB  = linv + (size_t)b * T_;
    const u16*   VtB = Vt   + (size_t)b * H_ * T_;

    floatx4 acc[8] = {};

    // prefetch registers for one chunk: S (2x short8), m/linv (8x float4)
    short8 sc[2];  float4 mc[2][2], lc[2][2];

    int ci = w;
    if (ci < nchunks) {
        const u16* Sc = SB + ((size_t)ci * T_ + t) * 64;
        const int  s0 = ci * 64;
        #pragma unroll
        for (int kk = 0; kk < 2; ++kk) {
            const int sl = kk * 32 + q * 8;
            sc[kk]    = *(const short8*)&Sc[sl];
            mc[kk][0] = *(const float4*)&mB[s0 + sl];
            mc[kk][1] = *(const float4*)&mB[s0 + sl + 4];
            lc[kk][0] = *(const float4*)&lB[s0 + sl];
            lc[kk][1] = *(const float4*)&lB[s0 + sl + 4];
        }
    }

    while (ci < nchunks) {
        const int s0 = ci * 64;
        const int cn = ci + 8;

        short8 sn[2];  float4 mn[2][2], ln[2][2];
        if (cn < nchunks) {                           // issue next-chunk loads
            const u16* Sc = SB + ((size_t)cn * T_ + t) * 64;
            const int  s0n = cn * 64;
            #pragma unroll
            for (int kk = 0; kk < 2; ++kk) {
                const int sl = kk * 32 + q * 8;
                sn[kk]    = *(const short8*)&Sc[sl];
                mn[kk][0] = *(const float4*)&mB[s0n + sl];
                mn[kk][1] = *(const float4*)&mB[s0n + sl + 4];
                ln[kk][0] = *(const float4*)&lB[s0n + sl];
                ln[kk][1] = *(const float4*)&lB[s0n + sl + 4];
            }
        }

        #pragma unroll
        for (int kk = 0; kk < 2; ++kk) {
            const int sb = s0 + kk * 32 + q * 8;      // global s base
            float mv[8], lv[8];
            *(float4*)&mv[0] = mc[kk][0];  *(float4*)&mv[4] = mc[kk][1];
            *(float4*)&lv[0] = lc[kk][0];  *(float4*)&lv[4] = lc[kk][1];

            short8 af;
            #pragma unroll
            for (int j = 0; j < 8; ++j) {
                float wj = 0.f;
                if (sb + j <= t)
                    wj = __expf(bf2f((u16)sc[kk][j]) - mv[j]) * lv[j];
                af[j] = (short)f2bf(wj);
            }
            #pragma unroll
            for (int nt = 0; nt < 8; ++nt) {
                short8 bf = *(const short8*)&VtB[(size_t)(16 * nt + r) * T_ + sb];
                acc[nt] = __builtin_amdgcn_mfma_f32_16x16x32_bf16(af, bf, acc[nt], 0, 0, 0);
            }
        }

        #pragma unroll
        for (int kk = 0; kk < 2; ++kk) {              // rotate pipeline regs
            sc[kk] = sn[kk];
            mc[kk][0] = mn[kk][0];  mc[kk][1] = mn[kk][1];
            lc[kk][0] = ln[kk][0];  lc[kk][1] = ln[kk][1];
        }
        ci = cn;
    }

    __shared__ float red[8][16 * RST];                // 67.6 KB, padded rows
    #pragma unroll
    for (int nt = 0; nt < 8; ++nt)
        #pragma unroll
        for (int reg = 0; reg < 4; ++reg)
            red[w][(q * 4 + reg) * RST + 16 * nt + r] = acc[nt][reg];
    __syncthreads();

    float* outB = out + ((size_t)b * T_ + t0) * H_;
    for (int i = threadIdx.x; i < 16 * 128; i += 512) {
        const int row = i >> 7, col = i & 127;
        float sum = 0.f;
        #pragma unroll
        for (int g = 0; g < 8; ++g) sum += red[g][row * RST + col];
        outB[i] = sum;
    }
}

// ---------------------------------------------------------------------------
extern "C" void kernel_launch(void* const* d_in, const int* in_sizes, int n_in,
                              void* d_out, int out_size, void* d_ws, size_t ws_size,
                              hipStream_t stream) {
    const float* x  = (const float*)d_in[0];
    const float* Wq = (const float*)d_in[1];
    const float* Wk = (const float*)d_in[2];
    const float* Wv = (const float*)d_in[3];
    float* out = (float*)d_out;

    // workspace: S3 bf16 [B][32][T][64] (32 MB), m, linv, Wt, Qb, Kb, Vt.
    u16*   S    = (u16*)d_ws;                          // 32 MB
    float* m    = (float*)(S + (size_t)B_ * T_ * T_);
    float* linv = m + (size_t)B_ * T_;
    u16*   Wt   = (u16*)(linv + (size_t)B_ * T_);      // 0.75 MB
    u16*   Qb   = Wt + (size_t)3 * H_ * C_;            // 2 MB
    u16*   Kb   = Qb + (size_t)B_ * T_ * H_;           // 2 MB
    u16*   Vt   = Kb + (size_t)B_ * T_ * H_;           // 2 MB
    // total ~39 MB

    // d_out staging: pm/pl (1 MB) written by scores, read by stats_reduce,
    // then out_kernel overwrites all 4 MB.
    float* pm = (float*)d_out;
    float* pl = pm + (size_t)B_ * NCHUNK * T_;

    convert_w_kernel  <<<dim3(C_ / 64, H_ / 64, 3),    dim3(256), 0, stream>>>(Wq, Wk, Wv, Wt);
    qkv_gemm_kernel   <<<dim3(B_ * T_ / 64, 3),        dim3(256), 0, stream>>>(x, Wt, Qb, Kb, Vt);
    scores_kernel     <<<dim3(16, 16, B_),             dim3(256), 0, stream>>>(Qb, Kb, S, pm, pl);
    stats_reduce_kernel<<<dim3(B_ * T_ / 256),         dim3(256), 0, stream>>>(pm, pl, m, linv);
    out_kernel        <<<dim3(T_ / 16, B_),            dim3(512), 0, stream>>>(S, Vt, m, linv, out);
}